// Round 1
// baseline (9290.544 us; speedup 1.0000x reference)
//
#include <hip/hip_runtime.h>
#include <hip/hip_bf16.h>
#include <cstdint>

#define BB 64
#define TT 512
#define II 1024
#define HH 1024
#define G4H 4096
#define KTOT 2048

typedef __attribute__((ext_vector_type(8))) short bf16x8;
typedef __attribute__((ext_vector_type(4))) float f32x4;
typedef __attribute__((ext_vector_type(8))) ushort ushort8v;
typedef __attribute__((ext_vector_type(4))) ushort ushort4v;

__device__ __forceinline__ ushort f2b(float f) {
  union { float f; uint32_t u; } v; v.f = f;
  uint32_t r = v.u + 0x7fffu + ((v.u >> 16) & 1u);
  return (ushort)(r >> 16);
}

__device__ __forceinline__ float sigm(float x) { return 1.0f / (1.0f + __expf(-x)); }
// tanh via 1 - 2/(e^{2x}+1): no inf/inf NaN at large |x|
__device__ __forceinline__ float tanh_f(float x) {
  float e = __expf(2.0f * x);
  return 1.0f - 2.0f / (e + 1.0f);
}

// Prep: fused bf16 weights Wc[c][k] (k<H: W_hh[c][k], k>=H: W_ih[c][k-H]),
// bias = bias_ih + bias_hh, initial h (bf16) and c (f32) buffers.
__global__ void k_prep(const float* __restrict__ wih, const float* __restrict__ whh,
                       const float* __restrict__ bih, const float* __restrict__ bhh,
                       const float* __restrict__ hx, const float* __restrict__ cx,
                       ushort* __restrict__ Wc, float* __restrict__ bias,
                       ushort* __restrict__ hbuf0, float* __restrict__ cbuf) {
  const int tid = blockIdx.x * blockDim.x + threadIdx.x;
  const int nth = gridDim.x * blockDim.x;
  for (int idx = tid; idx < G4H * (KTOT / 4); idx += nth) {
    const int c = idx >> 9;            // KTOT/4 = 512 vec4 groups per row
    const int k = (idx & 511) << 2;
    const float* src = (k < HH) ? (whh + (size_t)c * HH + k)
                                : (wih + (size_t)c * II + (k - HH));
    f32x4 v = *(const f32x4*)src;
    ushort4v o;
    o[0] = f2b(v[0]); o[1] = f2b(v[1]); o[2] = f2b(v[2]); o[3] = f2b(v[3]);
    *(ushort4v*)(Wc + (size_t)c * KTOT + k) = o;
  }
  for (int idx = tid; idx < G4H; idx += nth) bias[idx] = bih[idx] + bhh[idx];
  for (int idx = tid; idx < BB * HH; idx += nth) {
    hbuf0[idx] = f2b(hx[idx]);
    cbuf[idx] = cx[idx];
  }
}

// x [B][T][I] f32 -> xb [T][B][I] bf16
__global__ void k_convx(const float* __restrict__ x, ushort* __restrict__ xb) {
  const int tid = blockIdx.x * blockDim.x + threadIdx.x;
  const int nth = gridDim.x * blockDim.x;
  for (int idx = tid; idx < TT * BB * (II / 8); idx += nth) {
    const int i8 = idx & 127;          // II/8 = 128 groups
    const int tb = idx >> 7;           // t*B + b
    const int t = tb >> 6, b = tb & 63;
    const float* src = x + ((size_t)b * TT + t) * II + (size_t)i8 * 8;
    f32x4 v0 = *(const f32x4*)src;
    f32x4 v1 = *(const f32x4*)(src + 4);
    ushort8v o;
    o[0] = f2b(v0[0]); o[1] = f2b(v0[1]); o[2] = f2b(v0[2]); o[3] = f2b(v0[3]);
    o[4] = f2b(v1[0]); o[5] = f2b(v1[1]); o[6] = f2b(v1[2]); o[7] = f2b(v1[3]);
    *(ushort8v*)(xb + (size_t)idx * 8) = o;
  }
}

// One timestep. Grid 256 blocks x 256 threads.
// Block: mg = bid&1 (32 batch rows), cg = bid>>1 (8 h-indices).
// 4 waves: mt = w&1 (16-row M-tile), ct = w>>1 (16-wide col-tile; ct0={i,f}, ct1={g,o}).
template<bool XB>
__global__ void __launch_bounds__(256)
k_step(const ushort* __restrict__ Wc, const float* __restrict__ bias,
       const ushort* __restrict__ hprev, ushort* __restrict__ hnext,
       float* __restrict__ cbuf, const ushort* __restrict__ xb,
       const float* __restrict__ x,
       const float* __restrict__ wci, const float* __restrict__ wcf,
       const float* __restrict__ wco, float* __restrict__ out, int t) {
  __shared__ float pre[32][33];
  const int lane = threadIdx.x & 63;
  const int w = threadIdx.x >> 6;
  const int mt = w & 1, ct = w >> 1;
  const int mg = blockIdx.x & 1, cg = blockIdx.x >> 1;
  const int l15 = lane & 15, kg = lane >> 4;
  const int arow = mg * 32 + mt * 16 + l15;       // batch row for A frags
  const int gate = ct * 2 + (l15 >> 3);
  const int hl = l15 & 7;
  const int gcol = gate * HH + cg * 8 + hl;       // global gate column

  const ushort* wr = Wc + (size_t)gcol * KTOT + kg * 8;
  const ushort* hr = hprev + (size_t)arow * HH + kg * 8;

  f32x4 acc0 = {0.f, 0.f, 0.f, 0.f};
  f32x4 acc1 = {0.f, 0.f, 0.f, 0.f};

  // h part (K = 0..1023)
  #pragma unroll 8
  for (int ks = 0; ks < 32; ks += 2) {
    bf16x8 a0 = *(const bf16x8*)(hr + ks * 32);
    bf16x8 b0 = *(const bf16x8*)(wr + ks * 32);
    acc0 = __builtin_amdgcn_mfma_f32_16x16x32_bf16(a0, b0, acc0, 0, 0, 0);
    bf16x8 a1 = *(const bf16x8*)(hr + ks * 32 + 32);
    bf16x8 b1 = *(const bf16x8*)(wr + ks * 32 + 32);
    acc1 = __builtin_amdgcn_mfma_f32_16x16x32_bf16(a1, b1, acc1, 0, 0, 0);
  }
  // x part (K = 1024..2047)
  const ushort* wrx = wr + II;
  if (XB) {
    const ushort* xr = xb + ((size_t)t * BB + arow) * II + kg * 8;
    #pragma unroll 8
    for (int ks = 0; ks < 32; ks += 2) {
      bf16x8 a0 = *(const bf16x8*)(xr + ks * 32);
      bf16x8 b0 = *(const bf16x8*)(wrx + ks * 32);
      acc0 = __builtin_amdgcn_mfma_f32_16x16x32_bf16(a0, b0, acc0, 0, 0, 0);
      bf16x8 a1 = *(const bf16x8*)(xr + ks * 32 + 32);
      bf16x8 b1 = *(const bf16x8*)(wrx + ks * 32 + 32);
      acc1 = __builtin_amdgcn_mfma_f32_16x16x32_bf16(a1, b1, acc1, 0, 0, 0);
    }
  } else {
    const float* xr = x + ((size_t)arow * TT + t) * II + kg * 8;
    #pragma unroll 4
    for (int ks = 0; ks < 32; ++ks) {
      f32x4 v0 = *(const f32x4*)(xr + ks * 32);
      f32x4 v1 = *(const f32x4*)(xr + ks * 32 + 4);
      bf16x8 a;
      a[0] = (short)f2b(v0[0]); a[1] = (short)f2b(v0[1]);
      a[2] = (short)f2b(v0[2]); a[3] = (short)f2b(v0[3]);
      a[4] = (short)f2b(v1[0]); a[5] = (short)f2b(v1[1]);
      a[6] = (short)f2b(v1[2]); a[7] = (short)f2b(v1[3]);
      bf16x8 b0 = *(const bf16x8*)(wrx + ks * 32);
      acc0 = __builtin_amdgcn_mfma_f32_16x16x32_bf16(a, b0, acc0, 0, 0, 0);
    }
  }
  f32x4 acc = acc0 + acc1;

  // C/D layout: col = lane&15, row = (lane>>4)*4 + j  [measured m89]
  const float bv = bias[gcol];
  const int lr0 = mt * 16 + kg * 4;
  const int lc2 = ct * 16 + l15;
  #pragma unroll
  for (int j = 0; j < 4; ++j) pre[lr0 + j][lc2] = acc[j] + bv;
  __syncthreads();

  // gate update: thread -> (local row, h-local); 32*8 = 256
  const int tid = threadIdx.x;
  const int lr = tid >> 3;
  const int hl2 = tid & 7;
  const int b = mg * 32 + lr;
  const int hi = cg * 8 + hl2;
  const float ip = pre[lr][hl2];
  const float fp = pre[lr][8 + hl2];
  const float gp = pre[lr][16 + hl2];
  const float op = pre[lr][24 + hl2];
  const float c = cbuf[b * HH + hi];
  const float ig = sigm(ip + wci[hi] * c);
  const float fg = sigm(fp + wcf[hi] * c);
  const float gg = tanh_f(gp);
  const float cy = fg * c + ig * gg;
  const float og = sigm(op + wco[hi] * cy);
  const float hy = og * tanh_f(cy);
  cbuf[b * HH + hi] = cy;
  hnext[b * HH + hi] = f2b(hy);
  out[((size_t)b * TT + t) * HH + hi] = hy;
}

extern "C" void kernel_launch(void* const* d_in, const int* in_sizes, int n_in,
                              void* d_out, int out_size, void* d_ws, size_t ws_size,
                              hipStream_t stream) {
  const float* x   = (const float*)d_in[0];
  const float* hx  = (const float*)d_in[1];
  const float* cx  = (const float*)d_in[2];
  const float* wih = (const float*)d_in[3];
  const float* whh = (const float*)d_in[4];
  const float* bih = (const float*)d_in[5];
  const float* bhh = (const float*)d_in[6];
  const float* wci = (const float*)d_in[7];
  const float* wcf = (const float*)d_in[8];
  const float* wco = (const float*)d_in[9];
  float* out = (float*)d_out;

  char* ws = (char*)d_ws;
  ushort* Wc   = (ushort*)(ws);                 // 16,777,216 B
  float*  bias = (float*)(ws + 16777216);       // 16,384 B
  ushort* hbuf = (ushort*)(ws + 16793600);      // 262,144 B (2 ping-pong buffers)
  float*  cbuf = (float*)(ws + 17055744);       // 262,144 B
  ushort* xb   = (ushort*)(ws + 17317888);      // 67,108,864 B
  const size_t need_xb = 17317888ull + 67108864ull;
  const bool use_xb = ws_size >= need_xb;

  k_prep<<<512, 256, 0, stream>>>(wih, whh, bih, bhh, hx, cx, Wc, bias, hbuf, cbuf);
  if (use_xb) k_convx<<<1024, 256, 0, stream>>>(x, xb);

  for (int t = 0; t < TT; ++t) {
    const ushort* hp = hbuf + (size_t)(t & 1) * BB * HH;
    ushort* hn = hbuf + (size_t)((t + 1) & 1) * BB * HH;
    if (use_xb)
      k_step<true><<<256, 256, 0, stream>>>(Wc, bias, hp, hn, cbuf, xb, x,
                                            wci, wcf, wco, out, t);
    else
      k_step<false><<<256, 256, 0, stream>>>(Wc, bias, hp, hn, cbuf, xb, x,
                                             wci, wcf, wco, out, t);
  }
  // state outputs = INITIAL (hx, cx), per reference
  hipMemcpyAsync(out + 33554432, hx, (size_t)BB * HH * 4,
                 hipMemcpyDeviceToDevice, stream);
  hipMemcpyAsync(out + 33554432 + 65536, cx, (size_t)BB * HH * 4,
                 hipMemcpyDeviceToDevice, stream);
}